// Round 1
// baseline (2661.865 us; speedup 1.0000x reference)
//
#include <hip/hip_runtime.h>

// SNN forward: 3x (conv3x3 -> tdBN -> LIF -> maxpool2) + 2x (FC -> LIF)
// Shapes: x [16,32,1,32,400] -> pooled1 [16,32,6,16,200] -> pooled2 [16,32,6,8,100]
//         -> pooled3 [16,32,6,4,50] -> fc1 [16,32,100] -> fc2/out [16,32,2]

namespace {

constexpr int T = 16, B = 32;
constexpr int H1 = 32, W1 = 400, P1H = 16, P1W = 200;
constexpr int H2 = 16, W2 = 200, P2H = 8,  P2W = 100;
constexpr int H3 = 8,  W3 = 100, P3H = 4,  P3W = 50;

constexpr int NB1 = 512, NB2 = 256, NB3 = 128;  // stats grid sizes

// workspace byte offsets
constexpr size_t OFF_PART1 = 0;                                    // NB1*12 doubles
constexpr size_t OFF_PART2 = OFF_PART1 + (size_t)NB1 * 12 * 8;     // NB2*12 doubles
constexpr size_t OFF_PART3 = OFF_PART2 + (size_t)NB2 * 12 * 8;     // NB3*12 doubles
constexpr size_t OFF_STATS = OFF_PART3 + (size_t)NB3 * 12 * 8;     // 6x 8-float slots
constexpr size_t OFF_POOL1 = 98304;
constexpr size_t OFF_POOL2 = OFF_POOL1 + (size_t)T * B * 6 * P1H * P1W * 4;
constexpr size_t OFF_POOL3 = OFF_POOL2 + (size_t)T * B * 6 * P2H * P2W * 4;
constexpr size_t OFF_U1    = OFF_POOL3 + (size_t)T * B * 6 * P3H * P3W * 4;
constexpr size_t OFF_S1    = OFF_U1 + (size_t)T * B * 100 * 4;

} // namespace

__device__ __forceinline__ float lif_step(float& v, float y) {
  v = v + (y - v) * 0.5f;                 // tau=2, decay_input
  float sp = (v >= 1.0f) ? 1.0f : 0.0f;   // threshold 1.0
  v = (sp > 0.0f) ? 0.0f : v;             // hard reset
  return sp;
}

// Block-level reduction of 12 doubles (6 sums + 6 sumsq) -> partials[block*12..]
__device__ __forceinline__ void reduce12(double* s, double* q, double* partials) {
  __shared__ double lds[4][12];
  int lane = threadIdx.x & 63, wid = threadIdx.x >> 6;
#pragma unroll
  for (int k = 0; k < 12; k++) {
    double v = (k < 6) ? s[k] : q[k - 6];
#pragma unroll
    for (int off = 32; off >= 1; off >>= 1) v += __shfl_down(v, off, 64);
    if (lane == 0) lds[wid][k] = v;
  }
  __syncthreads();
  if (threadIdx.x < 12) {
    double v = lds[0][threadIdx.x] + lds[1][threadIdx.x] + lds[2][threadIdx.x] + lds[3][threadIdx.x];
    partials[(size_t)blockIdx.x * 12 + threadIdx.x] = v;
  }
}

// ---- pass 1, block 1: conv(1->6) stats only ----
__global__ void conv1_stats(const float* __restrict__ x, const float* __restrict__ w1,
                            double* __restrict__ partials) {
  const int NP = T * B * H1 * W1;
  float w[54];
#pragma unroll
  for (int k = 0; k < 54; k++) w[k] = w1[k];
  double s[6] = {0, 0, 0, 0, 0, 0}, q[6] = {0, 0, 0, 0, 0, 0};
  for (int p = blockIdx.x * blockDim.x + threadIdx.x; p < NP; p += gridDim.x * blockDim.x) {
    int tb = p / (H1 * W1);
    int rem = p - tb * (H1 * W1);
    int h = rem / W1, wc = rem - (rem / W1) * W1;
    const float* xb = x + (size_t)tb * H1 * W1;
    float patch[9];
#pragma unroll
    for (int ky = 0; ky < 3; ky++) {
      int hh = h + ky - 1;
#pragma unroll
      for (int kx = 0; kx < 3; kx++) {
        int ww = wc + kx - 1;
        patch[ky * 3 + kx] = (hh >= 0 && hh < H1 && ww >= 0 && ww < W1) ? xb[hh * W1 + ww] : 0.0f;
      }
    }
#pragma unroll
    for (int o = 0; o < 6; o++) {
      float acc = 0.0f;
#pragma unroll
      for (int k = 0; k < 9; k++) acc = fmaf(patch[k], w[o * 9 + k], acc);
      s[o] += (double)acc;
      q[o] += (double)acc * (double)acc;
    }
  }
  reduce12(s, q, partials);
}

// ---- pass 1, blocks 2/3: conv(6->6) stats only ----
template <int H, int W>
__global__ void conv6_stats(const float* __restrict__ in, const float* __restrict__ wt,
                            double* __restrict__ partials) {
  __shared__ float wsm[324];
  for (int k = threadIdx.x; k < 324; k += blockDim.x) wsm[k] = wt[k];
  __syncthreads();
  const int HW = H * W;
  const int NP = T * B * HW;
  double s[6] = {0, 0, 0, 0, 0, 0}, q[6] = {0, 0, 0, 0, 0, 0};
  for (int p = blockIdx.x * blockDim.x + threadIdx.x; p < NP; p += gridDim.x * blockDim.x) {
    int tb = p / HW;
    int rem = p - tb * HW;
    int h = rem / W, wc = rem - (rem / W) * W;
    const float* xb = in + (size_t)tb * 6 * HW;
    float acc[6] = {0, 0, 0, 0, 0, 0};
#pragma unroll
    for (int i = 0; i < 6; i++) {
      float patch[9];
#pragma unroll
      for (int ky = 0; ky < 3; ky++) {
        int hh = h + ky - 1;
#pragma unroll
        for (int kx = 0; kx < 3; kx++) {
          int ww = wc + kx - 1;
          patch[ky * 3 + kx] =
              (hh >= 0 && hh < H && ww >= 0 && ww < W) ? xb[i * HW + hh * W + ww] : 0.0f;
        }
      }
#pragma unroll
      for (int o = 0; o < 6; o++) {
        float a = acc[o];
#pragma unroll
        for (int k = 0; k < 9; k++) a = fmaf(patch[k], wsm[(o * 6 + i) * 9 + k], a);
        acc[o] = a;
      }
    }
#pragma unroll
    for (int o = 0; o < 6; o++) {
      s[o] += (double)acc[o];
      q[o] += (double)acc[o] * (double)acc[o];
    }
  }
  reduce12(s, q, partials);
}

// ---- finalize: partials -> mean[6], sg[6] (= gamma * rsqrt(var+eps)) ----
__global__ void finalize_stats(const double* __restrict__ partials, int nb, double n,
                               const float* __restrict__ gamma,
                               float* __restrict__ mean_out, float* __restrict__ sg_out) {
  __shared__ double sums[12];
  int k = threadIdx.x;
  if (k < 12) {
    double acc = 0.0;
    for (int b = 0; b < nb; b++) acc += partials[(size_t)b * 12 + k];
    sums[k] = acc;
  }
  __syncthreads();
  if (k < 6) {
    double mean = sums[k] / n;
    double var = sums[k + 6] / n - mean * mean;
    double invstd = 1.0 / sqrt(var + 1e-5);
    mean_out[k] = (float)mean;
    sg_out[k] = (float)(invstd * (double)gamma[k]);
  }
}

// ---- pass 2, block 1: conv(1->6)+BN+LIF+pool fused ----
__global__ void block1_fuse(const float* __restrict__ x, const float* __restrict__ w1,
                            const float* __restrict__ mean, const float* __restrict__ sg,
                            const float* __restrict__ beta, float* __restrict__ out) {
  int idx = blockIdx.x * blockDim.x + threadIdx.x;
  if (idx >= B * P1H * P1W) return;
  int b = idx / (P1H * P1W);
  int rem = idx - b * (P1H * P1W);
  int ph = rem / P1W, pw = rem - (rem / P1W) * P1W;

  float w[54];
#pragma unroll
  for (int k = 0; k < 54; k++) w[k] = w1[k];
  float m[6], s_[6], be[6];
#pragma unroll
  for (int o = 0; o < 6; o++) { m[o] = mean[o]; s_[o] = sg[o]; be[o] = beta[o]; }

  float v[24];
#pragma unroll
  for (int k = 0; k < 24; k++) v[k] = 0.0f;

  int h0 = 2 * ph - 1, w0 = 2 * pw - 1;
  for (int t = 0; t < T; t++) {
    const float* xb = x + (size_t)(t * B + b) * H1 * W1;
    float patch[16];
#pragma unroll
    for (int r = 0; r < 4; r++) {
      int hh = h0 + r;
#pragma unroll
      for (int c = 0; c < 4; c++) {
        int ww = w0 + c;
        patch[r * 4 + c] = (hh >= 0 && hh < H1 && ww >= 0 && ww < W1) ? xb[hh * W1 + ww] : 0.0f;
      }
    }
#pragma unroll
    for (int o = 0; o < 6; o++) {
      float smax = 0.0f;
#pragma unroll
      for (int dy = 0; dy < 2; dy++) {
#pragma unroll
        for (int dx = 0; dx < 2; dx++) {
          float acc = 0.0f;
#pragma unroll
          for (int ky = 0; ky < 3; ky++)
#pragma unroll
            for (int kx = 0; kx < 3; kx++)
              acc = fmaf(patch[(dy + ky) * 4 + dx + kx], w[o * 9 + ky * 3 + kx], acc);
          float y = (acc - m[o]) * s_[o] + be[o];
          float sp = lif_step(v[o * 4 + dy * 2 + dx], y);
          smax = fmaxf(smax, sp);
        }
      }
      out[((size_t)(t * B + b) * 6 + o) * (P1H * P1W) + ph * P1W + pw] = smax;
    }
  }
}

// ---- pass 2, blocks 2/3: conv(6->6)+BN+LIF+pool fused ----
template <int H, int W, int PH, int PW>
__global__ void block6_fuse(const float* __restrict__ in, const float* __restrict__ wt,
                            const float* __restrict__ mean, const float* __restrict__ sg,
                            const float* __restrict__ beta, float* __restrict__ out) {
  __shared__ float wsm[324];
  __shared__ float msm[6], ssm[6], bsm[6];
  for (int k = threadIdx.x; k < 324; k += blockDim.x) wsm[k] = wt[k];
  if (threadIdx.x < 6) {
    msm[threadIdx.x] = mean[threadIdx.x];
    ssm[threadIdx.x] = sg[threadIdx.x];
    bsm[threadIdx.x] = beta[threadIdx.x];
  }
  __syncthreads();

  int idx = blockIdx.x * blockDim.x + threadIdx.x;
  if (idx >= B * PH * PW) return;
  int b = idx / (PH * PW);
  int rem = idx - b * (PH * PW);
  int ph = rem / PW, pw = rem - (rem / PW) * PW;

  constexpr int HW = H * W;
  float v[24];
#pragma unroll
  for (int k = 0; k < 24; k++) v[k] = 0.0f;

  int h0 = 2 * ph - 1, w0 = 2 * pw - 1;
  for (int t = 0; t < T; t++) {
    const float* xb = in + (size_t)(t * B + b) * 6 * HW;
    float acc[24];
#pragma unroll
    for (int k = 0; k < 24; k++) acc[k] = 0.0f;
#pragma unroll
    for (int i = 0; i < 6; i++) {
      float patch[16];
#pragma unroll
      for (int r = 0; r < 4; r++) {
        int hh = h0 + r;
#pragma unroll
        for (int c = 0; c < 4; c++) {
          int ww = w0 + c;
          patch[r * 4 + c] =
              (hh >= 0 && hh < H && ww >= 0 && ww < W) ? xb[i * HW + hh * W + ww] : 0.0f;
        }
      }
#pragma unroll
      for (int o = 0; o < 6; o++) {
#pragma unroll
        for (int dy = 0; dy < 2; dy++) {
#pragma unroll
          for (int dx = 0; dx < 2; dx++) {
            float a = acc[o * 4 + dy * 2 + dx];
#pragma unroll
            for (int ky = 0; ky < 3; ky++)
#pragma unroll
              for (int kx = 0; kx < 3; kx++)
                a = fmaf(patch[(dy + ky) * 4 + dx + kx], wsm[(o * 6 + i) * 9 + ky * 3 + kx], a);
            acc[o * 4 + dy * 2 + dx] = a;
          }
        }
      }
    }
#pragma unroll
    for (int o = 0; o < 6; o++) {
      float smax = 0.0f;
#pragma unroll
      for (int p = 0; p < 4; p++) {
        float y = (acc[o * 4 + p] - msm[o]) * ssm[o] + bsm[o];
        float sp = lif_step(v[o * 4 + p], y);
        smax = fmaxf(smax, sp);
      }
      out[((size_t)(t * B + b) * 6 + o) * (PH * PW) + ph * PW + pw] = smax;
    }
  }
}

// ---- FC1 matmul: u1[t,b,o] = dot(pooled3[t,b,:1200], fw1[o,:1200]) ----
__global__ void fc1_mm(const float* __restrict__ p3, const float* __restrict__ fw1,
                       float* __restrict__ u1) {
  int idx = blockIdx.x * blockDim.x + threadIdx.x;
  if (idx >= T * B * 100) return;
  int o = idx % 100;
  int tb = idx / 100;
  const float4* x4 = (const float4*)(p3 + (size_t)tb * 1200);
  const float4* w4 = (const float4*)(fw1 + (size_t)o * 1200);
  float acc = 0.0f;
#pragma unroll 4
  for (int k = 0; k < 300; k++) {
    float4 a = x4[k], w = w4[k];
    acc = fmaf(a.x, w.x, acc);
    acc = fmaf(a.y, w.y, acc);
    acc = fmaf(a.z, w.z, acc);
    acc = fmaf(a.w, w.w, acc);
  }
  u1[idx] = acc;
}

// ---- FC1 LIF scan over T per (b,o) ----
__global__ void fc1_lif(const float* __restrict__ u1, float* __restrict__ s1) {
  int idx = blockIdx.x * blockDim.x + threadIdx.x;
  if (idx >= B * 100) return;
  float v = 0.0f;
  for (int t = 0; t < T; t++) {
    float sp = lif_step(v, u1[(size_t)t * B * 100 + idx]);
    s1[(size_t)t * B * 100 + idx] = sp;
  }
}

// ---- FC2 + LIF fused: out[t,b,o] ----
__global__ void fc2_fused(const float* __restrict__ s1, const float* __restrict__ fw2,
                          float* __restrict__ outp) {
  int idx = blockIdx.x * blockDim.x + threadIdx.x;
  if (idx >= B * 2) return;
  int b = idx >> 1, o = idx & 1;
  const float* wr = fw2 + o * 100;
  float v = 0.0f;
  for (int t = 0; t < T; t++) {
    const float* sr = s1 + (size_t)(t * B + b) * 100;
    float acc = 0.0f;
#pragma unroll
    for (int k = 0; k < 100; k++) acc = fmaf(sr[k], wr[k], acc);
    float sp = lif_step(v, acc);
    outp[(size_t)(t * B + b) * 2 + o] = sp;
  }
}

extern "C" void kernel_launch(void* const* d_in, const int* in_sizes, int n_in,
                              void* d_out, int out_size, void* d_ws, size_t ws_size,
                              hipStream_t stream) {
  const float* x   = (const float*)d_in[0];
  const float* w1  = (const float*)d_in[1];
  const float* g1  = (const float*)d_in[2];
  const float* b1  = (const float*)d_in[3];
  const float* w2  = (const float*)d_in[4];
  const float* g2  = (const float*)d_in[5];
  const float* b2  = (const float*)d_in[6];
  const float* w3  = (const float*)d_in[7];
  const float* g3  = (const float*)d_in[8];
  const float* b3  = (const float*)d_in[9];
  const float* fw1 = (const float*)d_in[10];
  const float* fw2 = (const float*)d_in[11];
  float* out = (float*)d_out;

  char* ws = (char*)d_ws;
  double* part1 = (double*)(ws + OFF_PART1);
  double* part2 = (double*)(ws + OFF_PART2);
  double* part3 = (double*)(ws + OFF_PART3);
  float* mean1 = (float*)(ws + OFF_STATS + 0);
  float* sg1   = (float*)(ws + OFF_STATS + 32);
  float* mean2 = (float*)(ws + OFF_STATS + 64);
  float* sg2   = (float*)(ws + OFF_STATS + 96);
  float* mean3 = (float*)(ws + OFF_STATS + 128);
  float* sg3   = (float*)(ws + OFF_STATS + 160);
  float* pool1 = (float*)(ws + OFF_POOL1);
  float* pool2 = (float*)(ws + OFF_POOL2);
  float* pool3 = (float*)(ws + OFF_POOL3);
  float* u1    = (float*)(ws + OFF_U1);
  float* s1    = (float*)(ws + OFF_S1);

  // Block 1
  conv1_stats<<<NB1, 256, 0, stream>>>(x, w1, part1);
  finalize_stats<<<1, 64, 0, stream>>>(part1, NB1, (double)T * B * H1 * W1, g1, mean1, sg1);
  {
    int n = B * P1H * P1W;
    block1_fuse<<<(n + 255) / 256, 256, 0, stream>>>(x, w1, mean1, sg1, b1, pool1);
  }
  // Block 2
  conv6_stats<H2, W2><<<NB2, 256, 0, stream>>>(pool1, w2, part2);
  finalize_stats<<<1, 64, 0, stream>>>(part2, NB2, (double)T * B * H2 * W2, g2, mean2, sg2);
  {
    int n = B * P2H * P2W;
    block6_fuse<H2, W2, P2H, P2W><<<(n + 255) / 256, 256, 0, stream>>>(pool1, w2, mean2, sg2, b2, pool2);
  }
  // Block 3
  conv6_stats<H3, W3><<<NB3, 256, 0, stream>>>(pool2, w3, part3);
  finalize_stats<<<1, 64, 0, stream>>>(part3, NB3, (double)T * B * H3 * W3, g3, mean3, sg3);
  {
    int n = B * P3H * P3W;
    block6_fuse<H3, W3, P3H, P3W><<<(n + 255) / 256, 256, 0, stream>>>(pool2, w3, mean3, sg3, b3, pool3);
  }
  // FC head
  {
    int n = T * B * 100;
    fc1_mm<<<(n + 255) / 256, 256, 0, stream>>>(pool3, fw1, u1);
  }
  {
    int n = B * 100;
    fc1_lif<<<(n + 255) / 256, 256, 0, stream>>>(u1, s1);
  }
  fc2_fused<<<1, 64, 0, stream>>>(s1, fw2, out);
}

// Round 5
// 2183.940 us; speedup vs baseline: 1.2188x; 1.2188x over previous
//
#include <hip/hip_runtime.h>

// SNN forward: 3x (conv3x3 -> tdBN -> LIF -> maxpool2) + 2x (FC -> LIF)
// Shapes: x [16,32,1,32,400] -> pooled1 [16,32,6,16,200] -> pooled2 [16,32,6,8,100]
//         -> pooled3 [16,32,6,4,50] -> fc1 [16,32,100] -> fc2/out [16,32,2]

namespace {

constexpr int T = 16, B = 32;
constexpr int H1 = 32, W1 = 400, P1H = 16, P1W = 200;
constexpr int H2 = 16, W2 = 200, P2H = 8,  P2W = 100;
constexpr int H3 = 8,  W3 = 100, P3H = 4,  P3W = 50;

constexpr int NB1 = 1024, NB2 = 512, NB3 = 256;  // stats grid sizes

// workspace byte offsets
constexpr size_t OFF_PART1 = 0;                                    // NB1*12 doubles = 98304
constexpr size_t OFF_PART2 = OFF_PART1 + (size_t)NB1 * 12 * 8;     // NB2*12 doubles
constexpr size_t OFF_PART3 = OFF_PART2 + (size_t)NB2 * 12 * 8;     // NB3*12 doubles
constexpr size_t OFF_STATS = OFF_PART3 + (size_t)NB3 * 12 * 8;     // 6x 8-float slots
constexpr size_t OFF_POOL1 = 262144;
constexpr size_t OFF_POOL2 = OFF_POOL1 + (size_t)T * B * 6 * P1H * P1W * 4;
constexpr size_t OFF_POOL3 = OFF_POOL2 + (size_t)T * B * 6 * P2H * P2W * 4;
constexpr size_t OFF_U1    = OFF_POOL3 + (size_t)T * B * 6 * P3H * P3W * 4;
constexpr size_t OFF_S1    = OFF_U1 + (size_t)T * B * 100 * 4;

} // namespace

__device__ __forceinline__ float lif_step(float& v, float y) {
  v = v + (y - v) * 0.5f;                 // tau=2, decay_input
  float sp = (v >= 1.0f) ? 1.0f : 0.0f;   // threshold 1.0
  v = (sp > 0.0f) ? 0.0f : v;             // hard reset
  return sp;
}

// Block-level reduction of 12 doubles (6 sums + 6 sumsq) -> partials[block*12..]
__device__ __forceinline__ void reduce12(double* s, double* q, double* partials) {
  __shared__ double lds[4][12];
  int lane = threadIdx.x & 63, wid = threadIdx.x >> 6;
#pragma unroll
  for (int k = 0; k < 12; k++) {
    double v = (k < 6) ? s[k] : q[k - 6];
#pragma unroll
    for (int off = 32; off >= 1; off >>= 1) v += __shfl_down(v, off, 64);
    if (lane == 0) lds[wid][k] = v;
  }
  __syncthreads();
  if (threadIdx.x < 12) {
    double v = lds[0][threadIdx.x] + lds[1][threadIdx.x] + lds[2][threadIdx.x] + lds[3][threadIdx.x];
    partials[(size_t)blockIdx.x * 12 + threadIdx.x] = v;
  }
}

// ---- pass 1, block 1: conv(1->6) stats only ----
__global__ void conv1_stats(const float* __restrict__ x, const float* __restrict__ w1,
                            double* __restrict__ partials) {
  const int NP = T * B * H1 * W1;
  float w[54];
#pragma unroll
  for (int k = 0; k < 54; k++) w[k] = w1[k];
  double s[6] = {0, 0, 0, 0, 0, 0}, q[6] = {0, 0, 0, 0, 0, 0};
  for (int p = blockIdx.x * blockDim.x + threadIdx.x; p < NP; p += gridDim.x * blockDim.x) {
    int tb = p / (H1 * W1);
    int rem = p - tb * (H1 * W1);
    int h = rem / W1, wc = rem - (rem / W1) * W1;
    const float* xb = x + (size_t)tb * H1 * W1;
    float patch[9];
#pragma unroll
    for (int ky = 0; ky < 3; ky++) {
      int hh = h + ky - 1;
#pragma unroll
      for (int kx = 0; kx < 3; kx++) {
        int ww = wc + kx - 1;
        patch[ky * 3 + kx] = (hh >= 0 && hh < H1 && ww >= 0 && ww < W1) ? xb[hh * W1 + ww] : 0.0f;
      }
    }
#pragma unroll
    for (int o = 0; o < 6; o++) {
      float acc = 0.0f;
#pragma unroll
      for (int k = 0; k < 9; k++) acc = fmaf(patch[k], w[o * 9 + k], acc);
      s[o] += (double)acc;
      q[o] += (double)acc * (double)acc;
    }
  }
  reduce12(s, q, partials);
}

// ---- pass 1, blocks 2/3: conv(6->6) stats only ----
template <int H, int W>
__global__ void conv6_stats(const float* __restrict__ in, const float* __restrict__ wt,
                            double* __restrict__ partials) {
  __shared__ float wsm[324];
  for (int k = threadIdx.x; k < 324; k += blockDim.x) wsm[k] = wt[k];
  __syncthreads();
  const int HW = H * W;
  const int NP = T * B * HW;
  double s[6] = {0, 0, 0, 0, 0, 0}, q[6] = {0, 0, 0, 0, 0, 0};
  for (int p = blockIdx.x * blockDim.x + threadIdx.x; p < NP; p += gridDim.x * blockDim.x) {
    int tb = p / HW;
    int rem = p - tb * HW;
    int h = rem / W, wc = rem - (rem / W) * W;
    const float* xb = in + (size_t)tb * 6 * HW;
    float acc[6] = {0, 0, 0, 0, 0, 0};
#pragma unroll
    for (int i = 0; i < 6; i++) {
      float patch[9];
#pragma unroll
      for (int ky = 0; ky < 3; ky++) {
        int hh = h + ky - 1;
#pragma unroll
        for (int kx = 0; kx < 3; kx++) {
          int ww = wc + kx - 1;
          patch[ky * 3 + kx] =
              (hh >= 0 && hh < H && ww >= 0 && ww < W) ? xb[i * HW + hh * W + ww] : 0.0f;
        }
      }
#pragma unroll
      for (int o = 0; o < 6; o++) {
        float a = acc[o];
#pragma unroll
        for (int k = 0; k < 9; k++) a = fmaf(patch[k], wsm[(o * 6 + i) * 9 + k], a);
        acc[o] = a;
      }
    }
#pragma unroll
    for (int o = 0; o < 6; o++) {
      s[o] += (double)acc[o];
      q[o] += (double)acc[o] * (double)acc[o];
    }
  }
  reduce12(s, q, partials);
}

// ---- finalize: partials -> mean[6], sg[6] (= gamma * rsqrt(var+eps)) ----
// 256 threads: thread t handles counter k=t%12 over strided chunks j=t/12 (21 chunks).
__global__ void finalize_stats(const double* __restrict__ partials, int nb, double n,
                               const float* __restrict__ gamma,
                               float* __restrict__ mean_out, float* __restrict__ sg_out) {
  __shared__ double lds[12][21];
  __shared__ double sums[12];
  int t = threadIdx.x;
  int k = t % 12, j = t / 12;
  if (t < 252) {
    double acc = 0.0;
    for (int b = j; b < nb; b += 21) acc += partials[(size_t)b * 12 + k];
    lds[k][j] = acc;
  }
  __syncthreads();
  if (t < 12) {
    double acc = 0.0;
#pragma unroll
    for (int j2 = 0; j2 < 21; j2++) acc += lds[t][j2];
    sums[t] = acc;
  }
  __syncthreads();
  if (t < 6) {
    double mean = sums[t] / n;
    double var = sums[t + 6] / n - mean * mean;
    double invstd = 1.0 / sqrt(var + 1e-5);
    mean_out[t] = (float)mean;
    sg_out[t] = (float)(invstd * (double)gamma[t]);
  }
}

// ---- pass 2, block 1: conv(1->6)+BN+LIF+pool fused, thread = (b,o,ph,pw) ----
__global__ void block1_fuse(const float* __restrict__ x, const float* __restrict__ w1,
                            const float* __restrict__ mean, const float* __restrict__ sg,
                            const float* __restrict__ beta, float* __restrict__ out) {
  int idx = blockIdx.x * blockDim.x + threadIdx.x;
  if (idx >= B * 6 * P1H * P1W) return;
  int pw = idx % P1W;
  int tmp = idx / P1W;
  int ph = tmp % P1H; tmp /= P1H;
  int o = tmp % 6;
  int b = tmp / 6;

  float w[9];
#pragma unroll
  for (int k = 0; k < 9; k++) w[k] = w1[o * 9 + k];
  float m = mean[o], s = sg[o], be = beta[o];

  float v[4] = {0.0f, 0.0f, 0.0f, 0.0f};
  int h0 = 2 * ph - 1, w0 = 2 * pw - 1;
  for (int t = 0; t < T; t++) {
    const float* xb = x + (size_t)(t * B + b) * H1 * W1;
    float patch[16];
#pragma unroll
    for (int r = 0; r < 4; r++) {
      int hh = h0 + r;
#pragma unroll
      for (int c = 0; c < 4; c++) {
        int ww = w0 + c;
        patch[r * 4 + c] = (hh >= 0 && hh < H1 && ww >= 0 && ww < W1) ? xb[hh * W1 + ww] : 0.0f;
      }
    }
    float smax = 0.0f;
#pragma unroll
    for (int dy = 0; dy < 2; dy++) {
#pragma unroll
      for (int dx = 0; dx < 2; dx++) {
        float acc = 0.0f;
#pragma unroll
        for (int ky = 0; ky < 3; ky++)
#pragma unroll
          for (int kx = 0; kx < 3; kx++)
            acc = fmaf(patch[(dy + ky) * 4 + dx + kx], w[ky * 3 + kx], acc);
        float y = (acc - m) * s + be;
        float sp = lif_step(v[dy * 2 + dx], y);
        smax = fmaxf(smax, sp);
      }
    }
    out[((size_t)(t * B + b) * 6 + o) * (P1H * P1W) + ph * P1W + pw] = smax;
  }
}

// ---- pass 2, blocks 2/3: conv(6->6)+BN+LIF+pool fused, thread = (b,o,ph,pw) ----
template <int H, int W, int PH, int PW>
__global__ void block6_fuse(const float* __restrict__ in, const float* __restrict__ wt,
                            const float* __restrict__ mean, const float* __restrict__ sg,
                            const float* __restrict__ beta, float* __restrict__ out) {
  __shared__ float wsm[324];
  for (int k = threadIdx.x; k < 324; k += blockDim.x) wsm[k] = wt[k];
  __syncthreads();

  int idx = blockIdx.x * blockDim.x + threadIdx.x;
  if (idx >= B * 6 * PH * PW) return;
  int pw = idx % PW;
  int tmp = idx / PW;
  int ph = tmp % PH; tmp /= PH;
  int o = tmp % 6;
  int b = tmp / 6;

  float m = mean[o], s = sg[o], be = beta[o];
  constexpr int HW = H * W;
  float v[4] = {0.0f, 0.0f, 0.0f, 0.0f};
  int h0 = 2 * ph - 1, w0 = 2 * pw - 1;

  for (int t = 0; t < T; t++) {
    const float* xb = in + (size_t)(t * B + b) * 6 * HW;
    float acc[4] = {0.0f, 0.0f, 0.0f, 0.0f};
#pragma unroll
    for (int i = 0; i < 6; i++) {
      float patch[16];
#pragma unroll
      for (int r = 0; r < 4; r++) {
        int hh = h0 + r;
#pragma unroll
        for (int c = 0; c < 4; c++) {
          int ww = w0 + c;
          patch[r * 4 + c] =
              (hh >= 0 && hh < H && ww >= 0 && ww < W) ? xb[i * HW + hh * W + ww] : 0.0f;
        }
      }
#pragma unroll
      for (int dy = 0; dy < 2; dy++) {
#pragma unroll
        for (int dx = 0; dx < 2; dx++) {
          float a = acc[dy * 2 + dx];
#pragma unroll
          for (int ky = 0; ky < 3; ky++)
#pragma unroll
            for (int kx = 0; kx < 3; kx++)
              a = fmaf(patch[(dy + ky) * 4 + dx + kx], wsm[(o * 6 + i) * 9 + ky * 3 + kx], a);
          acc[dy * 2 + dx] = a;
        }
      }
    }
    float smax = 0.0f;
#pragma unroll
    for (int p = 0; p < 4; p++) {
      float y = (acc[p] - m) * s + be;
      float sp = lif_step(v[p], y);
      smax = fmaxf(smax, sp);
    }
    out[((size_t)(t * B + b) * 6 + o) * (PH * PW) + ph * PW + pw] = smax;
  }
}

// ---- FC1 matmul: u1[t,b,o] = dot(pooled3[t,b,:1200], fw1[o,:1200]) ----
__global__ void fc1_mm(const float* __restrict__ p3, const float* __restrict__ fw1,
                       float* __restrict__ u1) {
  int idx = blockIdx.x * blockDim.x + threadIdx.x;
  if (idx >= T * B * 100) return;
  int o = idx % 100;
  int tb = idx / 100;
  const float4* x4 = (const float4*)(p3 + (size_t)tb * 1200);
  const float4* w4 = (const float4*)(fw1 + (size_t)o * 1200);
  float acc = 0.0f;
#pragma unroll 4
  for (int k = 0; k < 300; k++) {
    float4 a = x4[k], w = w4[k];
    acc = fmaf(a.x, w.x, acc);
    acc = fmaf(a.y, w.y, acc);
    acc = fmaf(a.z, w.z, acc);
    acc = fmaf(a.w, w.w, acc);
  }
  u1[idx] = acc;
}

// ---- FC1 LIF scan over T per (b,o) ----
__global__ void fc1_lif(const float* __restrict__ u1, float* __restrict__ s1) {
  int idx = blockIdx.x * blockDim.x + threadIdx.x;
  if (idx >= B * 100) return;
  float v = 0.0f;
  for (int t = 0; t < T; t++) {
    float sp = lif_step(v, u1[(size_t)t * B * 100 + idx]);
    s1[(size_t)t * B * 100 + idx] = sp;
  }
}

// ---- FC2 + LIF fused: out[t,b,o] ----
__global__ void fc2_fused(const float* __restrict__ s1, const float* __restrict__ fw2,
                          float* __restrict__ outp) {
  int idx = blockIdx.x * blockDim.x + threadIdx.x;
  if (idx >= B * 2) return;
  int b = idx >> 1, o = idx & 1;
  const float* wr = fw2 + o * 100;
  float v = 0.0f;
  for (int t = 0; t < T; t++) {
    const float* sr = s1 + (size_t)(t * B + b) * 100;
    float acc = 0.0f;
#pragma unroll
    for (int k = 0; k < 100; k++) acc = fmaf(sr[k], wr[k], acc);
    float sp = lif_step(v, acc);
    outp[(size_t)(t * B + b) * 2 + o] = sp;
  }
}

extern "C" void kernel_launch(void* const* d_in, const int* in_sizes, int n_in,
                              void* d_out, int out_size, void* d_ws, size_t ws_size,
                              hipStream_t stream) {
  const float* x   = (const float*)d_in[0];
  const float* w1  = (const float*)d_in[1];
  const float* g1  = (const float*)d_in[2];
  const float* b1  = (const float*)d_in[3];
  const float* w2  = (const float*)d_in[4];
  const float* g2  = (const float*)d_in[5];
  const float* b2  = (const float*)d_in[6];
  const float* w3  = (const float*)d_in[7];
  const float* g3  = (const float*)d_in[8];
  const float* b3  = (const float*)d_in[9];
  const float* fw1 = (const float*)d_in[10];
  const float* fw2 = (const float*)d_in[11];
  float* out = (float*)d_out;

  char* ws = (char*)d_ws;
  double* part1 = (double*)(ws + OFF_PART1);
  double* part2 = (double*)(ws + OFF_PART2);
  double* part3 = (double*)(ws + OFF_PART3);
  float* mean1 = (float*)(ws + OFF_STATS + 0);
  float* sg1   = (float*)(ws + OFF_STATS + 32);
  float* mean2 = (float*)(ws + OFF_STATS + 64);
  float* sg2   = (float*)(ws + OFF_STATS + 96);
  float* mean3 = (float*)(ws + OFF_STATS + 128);
  float* sg3   = (float*)(ws + OFF_STATS + 160);
  float* pool1 = (float*)(ws + OFF_POOL1);
  float* pool2 = (float*)(ws + OFF_POOL2);
  float* pool3 = (float*)(ws + OFF_POOL3);
  float* u1    = (float*)(ws + OFF_U1);
  float* s1    = (float*)(ws + OFF_S1);

  // Block 1
  conv1_stats<<<NB1, 256, 0, stream>>>(x, w1, part1);
  finalize_stats<<<1, 256, 0, stream>>>(part1, NB1, (double)T * B * H1 * W1, g1, mean1, sg1);
  {
    int n = B * 6 * P1H * P1W;  // 614400 -> 2400 blocks
    block1_fuse<<<(n + 255) / 256, 256, 0, stream>>>(x, w1, mean1, sg1, b1, pool1);
  }
  // Block 2
  conv6_stats<H2, W2><<<NB2, 256, 0, stream>>>(pool1, w2, part2);
  finalize_stats<<<1, 256, 0, stream>>>(part2, NB2, (double)T * B * H2 * W2, g2, mean2, sg2);
  {
    int n = B * 6 * P2H * P2W;  // 153600 -> 600 blocks
    block6_fuse<H2, W2, P2H, P2W><<<(n + 255) / 256, 256, 0, stream>>>(pool1, w2, mean2, sg2, b2, pool2);
  }
  // Block 3
  conv6_stats<H3, W3><<<NB3, 256, 0, stream>>>(pool2, w3, part3);
  finalize_stats<<<1, 256, 0, stream>>>(part3, NB3, (double)T * B * H3 * W3, g3, mean3, sg3);
  {
    int n = B * 6 * P3H * P3W;  // 38400 -> 150 blocks
    block6_fuse<H3, W3, P3H, P3W><<<(n + 255) / 256, 256, 0, stream>>>(pool2, w3, mean3, sg3, b3, pool3);
  }
  // FC head
  {
    int n = T * B * 100;
    fc1_mm<<<(n + 255) / 256, 256, 0, stream>>>(pool3, fw1, u1);
  }
  {
    int n = B * 100;
    fc1_lif<<<(n + 255) / 256, 256, 0, stream>>>(u1, s1);
  }
  fc2_fused<<<1, 64, 0, stream>>>(s1, fw2, out);
}

// Round 6
// 971.172 us; speedup vs baseline: 2.7409x; 2.2488x over previous
//
#include <hip/hip_runtime.h>

// SNN forward: 3x (conv3x3 -> tdBN -> LIF -> maxpool2) + 2x (FC -> LIF)
// Shapes: x [16,32,1,32,400] -> pooled1 [16,32,6,16,200] -> pooled2 [16,32,6,8,100]
//         -> pooled3 [16,32,6,4,50] -> fc1 [16,32,100] -> fc2/out [16,32,2]
//
// Structure: per conv block, pass-1 computes BN stats (conv recompute, no store),
// pass-2 is a fused conv+BN+LIF+pool kernel. Fuse kernels are LDS-tiled:
// one WG = (batch, 4x10 pooled tile, ALL 6 out-channels); per time-step the
// 6-channel input tile (+halo) is staged in LDS once (kills the 24x read
// amplification seen in round 5: FETCH 1.72 GB -> ~50 MB for block2).

namespace {

constexpr int T = 16, B = 32;
constexpr int H1 = 32, W1 = 400, P1H = 16, P1W = 200;
constexpr int H2 = 16, W2 = 200, P2H = 8,  P2W = 100;
constexpr int H3 = 8,  W3 = 100, P3H = 4,  P3W = 50;

constexpr int NB1 = 1024, NB2 = 512, NB3 = 256;  // stats grid sizes

// workspace byte offsets
constexpr size_t OFF_PART1 = 0;                                    // NB1*12 doubles = 98304
constexpr size_t OFF_PART2 = OFF_PART1 + (size_t)NB1 * 12 * 8;     // NB2*12 doubles
constexpr size_t OFF_PART3 = OFF_PART2 + (size_t)NB2 * 12 * 8;     // NB3*12 doubles
constexpr size_t OFF_STATS = OFF_PART3 + (size_t)NB3 * 12 * 8;     // 6x 8-float slots
constexpr size_t OFF_POOL1 = 262144;
constexpr size_t OFF_POOL2 = OFF_POOL1 + (size_t)T * B * 6 * P1H * P1W * 4;
constexpr size_t OFF_POOL3 = OFF_POOL2 + (size_t)T * B * 6 * P2H * P2W * 4;
constexpr size_t OFF_U1    = OFF_POOL3 + (size_t)T * B * 6 * P3H * P3W * 4;
constexpr size_t OFF_S1    = OFF_U1 + (size_t)T * B * 100 * 4;

} // namespace

__device__ __forceinline__ float lif_step(float& v, float y) {
  v = v + (y - v) * 0.5f;                 // tau=2, decay_input
  float sp = (v >= 1.0f) ? 1.0f : 0.0f;   // threshold 1.0
  v = (sp > 0.0f) ? 0.0f : v;             // hard reset
  return sp;
}

// Block-level reduction of 12 doubles (6 sums + 6 sumsq) -> partials[block*12..]
__device__ __forceinline__ void reduce12(double* s, double* q, double* partials) {
  __shared__ double lds[4][12];
  int lane = threadIdx.x & 63, wid = threadIdx.x >> 6;
#pragma unroll
  for (int k = 0; k < 12; k++) {
    double v = (k < 6) ? s[k] : q[k - 6];
#pragma unroll
    for (int off = 32; off >= 1; off >>= 1) v += __shfl_down(v, off, 64);
    if (lane == 0) lds[wid][k] = v;
  }
  __syncthreads();
  if (threadIdx.x < 12) {
    double v = lds[0][threadIdx.x] + lds[1][threadIdx.x] + lds[2][threadIdx.x] + lds[3][threadIdx.x];
    partials[(size_t)blockIdx.x * 12 + threadIdx.x] = v;
  }
}

// ---- pass 1, block 1: conv(1->6) stats only ----
__global__ void conv1_stats(const float* __restrict__ x, const float* __restrict__ w1,
                            double* __restrict__ partials) {
  const int NP = T * B * H1 * W1;
  float w[54];
#pragma unroll
  for (int k = 0; k < 54; k++) w[k] = w1[k];
  double s[6] = {0, 0, 0, 0, 0, 0}, q[6] = {0, 0, 0, 0, 0, 0};
  for (int p = blockIdx.x * blockDim.x + threadIdx.x; p < NP; p += gridDim.x * blockDim.x) {
    int tb = p / (H1 * W1);
    int rem = p - tb * (H1 * W1);
    int h = rem / W1, wc = rem - (rem / W1) * W1;
    const float* xb = x + (size_t)tb * H1 * W1;
    float patch[9];
#pragma unroll
    for (int ky = 0; ky < 3; ky++) {
      int hh = h + ky - 1;
#pragma unroll
      for (int kx = 0; kx < 3; kx++) {
        int ww = wc + kx - 1;
        patch[ky * 3 + kx] = (hh >= 0 && hh < H1 && ww >= 0 && ww < W1) ? xb[hh * W1 + ww] : 0.0f;
      }
    }
#pragma unroll
    for (int o = 0; o < 6; o++) {
      float acc = 0.0f;
#pragma unroll
      for (int k = 0; k < 9; k++) acc = fmaf(patch[k], w[o * 9 + k], acc);
      s[o] += (double)acc;
      q[o] += (double)acc * (double)acc;
    }
  }
  reduce12(s, q, partials);
}

// ---- pass 1, blocks 2/3: conv(6->6) stats only ----
template <int H, int W>
__global__ void conv6_stats(const float* __restrict__ in, const float* __restrict__ wt,
                            double* __restrict__ partials) {
  __shared__ float wsm[324];
  for (int k = threadIdx.x; k < 324; k += blockDim.x) wsm[k] = wt[k];
  __syncthreads();
  const int HW = H * W;
  const int NP = T * B * HW;
  double s[6] = {0, 0, 0, 0, 0, 0}, q[6] = {0, 0, 0, 0, 0, 0};
  for (int p = blockIdx.x * blockDim.x + threadIdx.x; p < NP; p += gridDim.x * blockDim.x) {
    int tb = p / HW;
    int rem = p - tb * HW;
    int h = rem / W, wc = rem - (rem / W) * W;
    const float* xb = in + (size_t)tb * 6 * HW;
    float acc[6] = {0, 0, 0, 0, 0, 0};
#pragma unroll
    for (int i = 0; i < 6; i++) {
      float patch[9];
#pragma unroll
      for (int ky = 0; ky < 3; ky++) {
        int hh = h + ky - 1;
#pragma unroll
        for (int kx = 0; kx < 3; kx++) {
          int ww = wc + kx - 1;
          patch[ky * 3 + kx] =
              (hh >= 0 && hh < H && ww >= 0 && ww < W) ? xb[i * HW + hh * W + ww] : 0.0f;
        }
      }
#pragma unroll
      for (int o = 0; o < 6; o++) {
        float a = acc[o];
#pragma unroll
        for (int k = 0; k < 9; k++) a = fmaf(patch[k], wsm[(o * 6 + i) * 9 + k], a);
        acc[o] = a;
      }
    }
#pragma unroll
    for (int o = 0; o < 6; o++) {
      s[o] += (double)acc[o];
      q[o] += (double)acc[o] * (double)acc[o];
    }
  }
  reduce12(s, q, partials);
}

// ---- finalize: partials -> mean[6], sg[6] (= gamma * rsqrt(var+eps)) ----
__global__ void finalize_stats(const double* __restrict__ partials, int nb, double n,
                               const float* __restrict__ gamma,
                               float* __restrict__ mean_out, float* __restrict__ sg_out) {
  __shared__ double lds[12][21];
  __shared__ double sums[12];
  int t = threadIdx.x;
  int k = t % 12, j = t / 12;
  if (t < 252) {
    double acc = 0.0;
    for (int b = j; b < nb; b += 21) acc += partials[(size_t)b * 12 + k];
    lds[k][j] = acc;
  }
  __syncthreads();
  if (t < 12) {
    double acc = 0.0;
#pragma unroll
    for (int j2 = 0; j2 < 21; j2++) acc += lds[t][j2];
    sums[t] = acc;
  }
  __syncthreads();
  if (t < 6) {
    double mean = sums[t] / n;
    double var = sums[t + 6] / n - mean * mean;
    double invstd = 1.0 / sqrt(var + 1e-5);
    mean_out[t] = (float)mean;
    sg_out[t] = (float)(invstd * (double)gamma[t]);
  }
}

// ---- pass 2, block 1: conv(1->6)+BN+LIF+pool, LDS-tiled ----
// WG = 256 threads; active = 6 o-channels x TH x TW pooled positions.
// Per t: stage input tile (2TH+2)x(2TW+2) (1 channel) in LDS, all o consume.
template <int TH, int TW>
__global__ void block1_fuse_lds(const float* __restrict__ x, const float* __restrict__ w1,
                                const float* __restrict__ mean, const float* __restrict__ sg,
                                const float* __restrict__ beta, float* __restrict__ out) {
  constexpr int NTH = P1H / TH, NTW = P1W / TW;
  constexpr int IH = 2 * TH + 2, IW = 2 * TW + 2;
  constexpr int TILE_N = IH * IW;
  constexpr int NACT = 6 * TH * TW;
  __shared__ float tile[IH][IW];

  int wg = blockIdx.x;
  int b = wg / (NTH * NTW);
  int tid2 = wg % (NTH * NTW);
  int ty = tid2 / NTW, tx = tid2 % NTW;
  int h_in0 = 2 * (ty * TH) - 1, w_in0 = 2 * (tx * TW) - 1;

  int tid = threadIdx.x;
  int o = 0, lph = 0, lpw = 0;
  if (tid < NACT) {
    o = tid / (TH * TW);
    int r = tid % (TH * TW);
    lph = r / TW; lpw = r % TW;
  }
  float w[9];
#pragma unroll
  for (int k = 0; k < 9; k++) w[k] = w1[o * 9 + k];
  float m = mean[o], s = sg[o], be = beta[o];
  float v[4] = {0.0f, 0.0f, 0.0f, 0.0f};

  for (int t = 0; t < T; t++) {
    __syncthreads();
    const float* xb = x + (size_t)(t * B + b) * (H1 * W1);
    for (int k = tid; k < TILE_N; k += blockDim.x) {
      int rr = k / IW, cc = k % IW;
      int hh = h_in0 + rr, ww = w_in0 + cc;
      tile[rr][cc] = (hh >= 0 && hh < H1 && ww >= 0 && ww < W1) ? xb[hh * W1 + ww] : 0.0f;
    }
    __syncthreads();
    if (tid < NACT) {
      int ry = 2 * lph, rx = 2 * lpw;
      float p[16];
#pragma unroll
      for (int r = 0; r < 4; r++)
#pragma unroll
        for (int c = 0; c < 4; c++) p[r * 4 + c] = tile[ry + r][rx + c];
      float smax = 0.0f;
#pragma unroll
      for (int dy = 0; dy < 2; dy++) {
#pragma unroll
        for (int dx = 0; dx < 2; dx++) {
          float acc = 0.0f;
#pragma unroll
          for (int ky = 0; ky < 3; ky++)
#pragma unroll
            for (int kx = 0; kx < 3; kx++)
              acc = fmaf(p[(dy + ky) * 4 + dx + kx], w[ky * 3 + kx], acc);
          float y = (acc - m) * s + be;
          float sp = lif_step(v[dy * 2 + dx], y);
          smax = fmaxf(smax, sp);
        }
      }
      out[((size_t)(t * B + b) * 6 + o) * (P1H * P1W) + (ty * TH + lph) * P1W + (tx * TW + lpw)] = smax;
    }
  }
}

// ---- pass 2, blocks 2/3: conv(6->6)+BN+LIF+pool, LDS-tiled ----
template <int H, int W, int PH, int PW, int TH, int TW>
__global__ void block6_fuse_lds(const float* __restrict__ in, const float* __restrict__ wt,
                                const float* __restrict__ mean, const float* __restrict__ sg,
                                const float* __restrict__ beta, float* __restrict__ out) {
  constexpr int NTH = PH / TH, NTW = PW / TW;
  constexpr int IH = 2 * TH + 2, IW = 2 * TW + 2;
  constexpr int TILE_N = IH * IW;
  constexpr int NACT = 6 * TH * TW;
  constexpr int HW = H * W;
  __shared__ float wsm[324];
  __shared__ float tile[6][IH][IW];

  for (int k = threadIdx.x; k < 324; k += blockDim.x) wsm[k] = wt[k];

  int wg = blockIdx.x;
  int b = wg / (NTH * NTW);
  int tid2 = wg % (NTH * NTW);
  int ty = tid2 / NTW, tx = tid2 % NTW;
  int h_in0 = 2 * (ty * TH) - 1, w_in0 = 2 * (tx * TW) - 1;

  int tid = threadIdx.x;
  int o = 0, lph = 0, lpw = 0;
  if (tid < NACT) {
    o = tid / (TH * TW);
    int r = tid % (TH * TW);
    lph = r / TW; lpw = r % TW;
  }
  float m = mean[o], s = sg[o], be = beta[o];
  float v[4] = {0.0f, 0.0f, 0.0f, 0.0f};

  for (int t = 0; t < T; t++) {
    __syncthreads();
    const float* xb = in + (size_t)(t * B + b) * 6 * HW;
    for (int k = tid; k < 6 * TILE_N; k += blockDim.x) {
      int i = k / TILE_N;
      int r2 = k % TILE_N;
      int rr = r2 / IW, cc = r2 % IW;
      int hh = h_in0 + rr, ww = w_in0 + cc;
      tile[i][rr][cc] = (hh >= 0 && hh < H && ww >= 0 && ww < W) ? xb[i * HW + hh * W + ww] : 0.0f;
    }
    __syncthreads();
    if (tid < NACT) {
      int ry = 2 * lph, rx = 2 * lpw;
      float acc[4] = {0.0f, 0.0f, 0.0f, 0.0f};
#pragma unroll
      for (int i = 0; i < 6; i++) {
        float p[16];
#pragma unroll
        for (int r = 0; r < 4; r++)
#pragma unroll
          for (int c = 0; c < 4; c++) p[r * 4 + c] = tile[i][ry + r][rx + c];
        const float* wo = &wsm[(o * 6 + i) * 9];
#pragma unroll
        for (int dy = 0; dy < 2; dy++)
#pragma unroll
          for (int dx = 0; dx < 2; dx++) {
            float a = acc[dy * 2 + dx];
#pragma unroll
            for (int ky = 0; ky < 3; ky++)
#pragma unroll
              for (int kx = 0; kx < 3; kx++)
                a = fmaf(p[(dy + ky) * 4 + dx + kx], wo[ky * 3 + kx], a);
            acc[dy * 2 + dx] = a;
          }
      }
      float smax = 0.0f;
#pragma unroll
      for (int p4 = 0; p4 < 4; p4++) {
        float y = (acc[p4] - m) * s + be;
        float sp = lif_step(v[p4], y);
        smax = fmaxf(smax, sp);
      }
      out[((size_t)(t * B + b) * 6 + o) * (PH * PW) + (ty * TH + lph) * PW + (tx * TW + lpw)] = smax;
    }
  }
}

// ---- FC1 matmul: u1[t,b,o] = dot(pooled3[t,b,:1200], fw1[o,:1200]) ----
__global__ void fc1_mm(const float* __restrict__ p3, const float* __restrict__ fw1,
                       float* __restrict__ u1) {
  int idx = blockIdx.x * blockDim.x + threadIdx.x;
  if (idx >= T * B * 100) return;
  int o = idx % 100;
  int tb = idx / 100;
  const float4* x4 = (const float4*)(p3 + (size_t)tb * 1200);
  const float4* w4 = (const float4*)(fw1 + (size_t)o * 1200);
  float acc = 0.0f;
#pragma unroll 4
  for (int k = 0; k < 300; k++) {
    float4 a = x4[k], w = w4[k];
    acc = fmaf(a.x, w.x, acc);
    acc = fmaf(a.y, w.y, acc);
    acc = fmaf(a.z, w.z, acc);
    acc = fmaf(a.w, w.w, acc);
  }
  u1[idx] = acc;
}

// ---- FC1 LIF scan over T per (b,o) ----
__global__ void fc1_lif(const float* __restrict__ u1, float* __restrict__ s1) {
  int idx = blockIdx.x * blockDim.x + threadIdx.x;
  if (idx >= B * 100) return;
  float v = 0.0f;
  for (int t = 0; t < T; t++) {
    float sp = lif_step(v, u1[(size_t)t * B * 100 + idx]);
    s1[(size_t)t * B * 100 + idx] = sp;
  }
}

// ---- FC2 + LIF fused: out[t,b,o] ----
__global__ void fc2_fused(const float* __restrict__ s1, const float* __restrict__ fw2,
                          float* __restrict__ outp) {
  int idx = blockIdx.x * blockDim.x + threadIdx.x;
  if (idx >= B * 2) return;
  int b = idx >> 1, o = idx & 1;
  const float* wr = fw2 + o * 100;
  float v = 0.0f;
  for (int t = 0; t < T; t++) {
    const float* sr = s1 + (size_t)(t * B + b) * 100;
    float acc = 0.0f;
#pragma unroll
    for (int k = 0; k < 100; k++) acc = fmaf(sr[k], wr[k], acc);
    float sp = lif_step(v, acc);
    outp[(size_t)(t * B + b) * 2 + o] = sp;
  }
}

extern "C" void kernel_launch(void* const* d_in, const int* in_sizes, int n_in,
                              void* d_out, int out_size, void* d_ws, size_t ws_size,
                              hipStream_t stream) {
  const float* x   = (const float*)d_in[0];
  const float* w1  = (const float*)d_in[1];
  const float* g1  = (const float*)d_in[2];
  const float* b1  = (const float*)d_in[3];
  const float* w2  = (const float*)d_in[4];
  const float* g2  = (const float*)d_in[5];
  const float* b2  = (const float*)d_in[6];
  const float* w3  = (const float*)d_in[7];
  const float* g3  = (const float*)d_in[8];
  const float* b3  = (const float*)d_in[9];
  const float* fw1 = (const float*)d_in[10];
  const float* fw2 = (const float*)d_in[11];
  float* out = (float*)d_out;

  char* ws = (char*)d_ws;
  double* part1 = (double*)(ws + OFF_PART1);
  double* part2 = (double*)(ws + OFF_PART2);
  double* part3 = (double*)(ws + OFF_PART3);
  float* mean1 = (float*)(ws + OFF_STATS + 0);
  float* sg1   = (float*)(ws + OFF_STATS + 32);
  float* mean2 = (float*)(ws + OFF_STATS + 64);
  float* sg2   = (float*)(ws + OFF_STATS + 96);
  float* mean3 = (float*)(ws + OFF_STATS + 128);
  float* sg3   = (float*)(ws + OFF_STATS + 160);
  float* pool1 = (float*)(ws + OFF_POOL1);
  float* pool2 = (float*)(ws + OFF_POOL2);
  float* pool3 = (float*)(ws + OFF_POOL3);
  float* u1    = (float*)(ws + OFF_U1);
  float* s1    = (float*)(ws + OFF_S1);

  // Block 1
  conv1_stats<<<NB1, 256, 0, stream>>>(x, w1, part1);
  finalize_stats<<<1, 256, 0, stream>>>(part1, NB1, (double)T * B * H1 * W1, g1, mean1, sg1);
  {
    // tiles: (16/4)x(200/10) = 80 per batch -> 2560 WGs, 240 active threads each
    int nwg = B * (P1H / 4) * (P1W / 10);
    block1_fuse_lds<4, 10><<<nwg, 256, 0, stream>>>(x, w1, mean1, sg1, b1, pool1);
  }
  // Block 2
  conv6_stats<H2, W2><<<NB2, 256, 0, stream>>>(pool1, w2, part2);
  finalize_stats<<<1, 256, 0, stream>>>(part2, NB2, (double)T * B * H2 * W2, g2, mean2, sg2);
  {
    // tiles: (8/4)x(100/10) = 20 per batch -> 640 WGs
    int nwg = B * (P2H / 4) * (P2W / 10);
    block6_fuse_lds<H2, W2, P2H, P2W, 4, 10><<<nwg, 256, 0, stream>>>(pool1, w2, mean2, sg2, b2, pool2);
  }
  // Block 3
  conv6_stats<H3, W3><<<NB3, 256, 0, stream>>>(pool2, w3, part3);
  finalize_stats<<<1, 256, 0, stream>>>(part3, NB3, (double)T * B * H3 * W3, g3, mean3, sg3);
  {
    // tiles: (4/4)x(50/10) = 5 per batch -> 160 WGs
    int nwg = B * (P3H / 4) * (P3W / 10);
    block6_fuse_lds<H3, W3, P3H, P3W, 4, 10><<<nwg, 256, 0, stream>>>(pool2, w3, mean3, sg3, b3, pool3);
  }
  // FC head
  {
    int n = T * B * 100;
    fc1_mm<<<(n + 255) / 256, 256, 0, stream>>>(pool3, fw1, u1);
  }
  {
    int n = B * 100;
    fc1_lif<<<(n + 255) / 256, 256, 0, stream>>>(u1, s1);
  }
  fc2_fused<<<1, 64, 0, stream>>>(s1, fw2, out);
}